// Round 4
// baseline (456.465 us; speedup 1.0000x reference)
//
#include <hip/hip_runtime.h>
#include <cstdint>
#include <cstddef>

#define B_TOK 1024
#define DD_IN 3072
#define RHID 128
#define NEXP 8
#define EHID 2048
#define NCLS 10
#define KHALF 1536
#define NTILE_MAX 23
#define PH_ROWS (NTILE_MAX * 128)   // 2944

typedef __attribute__((ext_vector_type(8))) short short8;
typedef __attribute__((ext_vector_type(4))) float floatx4;

// ---- helpers ------------------------------------------------------------
__device__ __forceinline__ unsigned short f2bf(float f) {
  unsigned u = __builtin_bit_cast(unsigned, f);
  u += 0x7fffu + ((u >> 16) & 1u);           // RNE
  return (unsigned short)(u >> 16);
}
__device__ __forceinline__ unsigned pk_bf16(float a, float b) {
  return (unsigned)f2bf(a) | ((unsigned)f2bf(b) << 16);
}
__device__ __forceinline__ float bf2f(unsigned short h) {
  unsigned u = ((unsigned)h) << 16;
  return __builtin_bit_cast(float, u);
}
__device__ __forceinline__ float bflo(unsigned w) { return bf2f((unsigned short)(w & 0xffffu)); }
__device__ __forceinline__ float bfhi(unsigned w) { return bf2f((unsigned short)(w >> 16)); }

// ---- router GEMM1 (fp32, split-K S=16): partial[s][tok][hid] ------------
// Also: converts x -> bf16 (xbf) since each block reads each x element once,
// and zeroes cnt[] (replaces the memset launch).
__global__ __launch_bounds__(256) void k_router_gemm(const float* __restrict__ x,
                                                     const float* __restrict__ rW1,
                                                     float* __restrict__ partial,
                                                     unsigned short* __restrict__ xbf,
                                                     int* __restrict__ cnt) {
  if (blockIdx.x == 0 && blockIdx.y == 0 && threadIdx.x < NEXP) cnt[threadIdx.x] = 0;
  const int ttile = blockIdx.x;   // 16 tiles x 64 tokens
  const int s = blockIdx.y;       // 16 K-slices x 192
  const int T0 = ttile * 64;
  const int K0 = s * 192;
  __shared__ float xs[16][64];     // [k][tok]
  __shared__ float wsm[16][132];   // [k][hid], +4 pad
  float acc[4][8];
#pragma unroll
  for (int i = 0; i < 4; i++)
#pragma unroll
    for (int j = 0; j < 8; j++) acc[i][j] = 0.f;
  const int tx = threadIdx.x & 15, ty = threadIdx.x >> 4;
  const int tid = threadIdx.x;

  const int xtok = tid >> 2, xk = (tid & 3) << 2;       // x loader coords
  const int wk0 = tid >> 5, wf0 = (tid & 31) << 2;      // rW1 loader (2 rounds)

  float4 pX, pW0, pW1;
  pX  = *(const float4*)(x + (size_t)(T0 + xtok) * DD_IN + K0 + xk);
  pW0 = *(const float4*)(rW1 + (size_t)(K0 + wk0) * RHID + wf0);
  pW1 = *(const float4*)(rW1 + (size_t)(K0 + wk0 + 8) * RHID + wf0);

  for (int kc = K0; kc < K0 + 192; kc += 16) {
    xs[xk + 0][xtok] = pX.x; xs[xk + 1][xtok] = pX.y;
    xs[xk + 2][xtok] = pX.z; xs[xk + 3][xtok] = pX.w;
    {  // bf16 convert side-channel (each x element touched exactly once grid-wide)
      uint2 u2;
      u2.x = pk_bf16(pX.x, pX.y); u2.y = pk_bf16(pX.z, pX.w);
      *(uint2*)(xbf + (size_t)(T0 + xtok) * DD_IN + kc + xk) = u2;
    }
    *(float4*)&wsm[wk0][wf0] = pW0;
    *(float4*)&wsm[wk0 + 8][wf0] = pW1;
    __syncthreads();
    if (kc + 16 < K0 + 192) {
      pX  = *(const float4*)(x + (size_t)(T0 + xtok) * DD_IN + kc + 16 + xk);
      pW0 = *(const float4*)(rW1 + (size_t)(kc + 16 + wk0) * RHID + wf0);
      pW1 = *(const float4*)(rW1 + (size_t)(kc + 16 + wk0 + 8) * RHID + wf0);
    }
#pragma unroll
    for (int kk = 0; kk < 16; kk++) {
      float wv[8], xv[4];
      *(float4*)&wv[0] = *(const float4*)&wsm[kk][tx * 8];
      *(float4*)&wv[4] = *(const float4*)&wsm[kk][tx * 8 + 4];
#pragma unroll
      for (int i = 0; i < 4; i++) xv[i] = xs[kk][ty * 4 + i];
#pragma unroll
      for (int i = 0; i < 4; i++)
#pragma unroll
        for (int j = 0; j < 8; j++) acc[i][j] += xv[i] * wv[j];
    }
    __syncthreads();
  }
#pragma unroll
  for (int i = 0; i < 4; i++) {
    float* p = partial + ((size_t)s * B_TOK + T0 + ty * 4 + i) * RHID + tx * 8;
    *(float4*)p = *(float4*)&acc[i][0];
    *(float4*)(p + 4) = *(float4*)&acc[i][4];
  }
}

// ---- router finalize: reduce partials, relu, logits, top-2, bucket build
// also initializes out = eb2 for its 4 tokens (sum of normalized weights == 1)
__global__ __launch_bounds__(256) void k_router_fin(const float* __restrict__ partial,
                                                    const float* __restrict__ rb1,
                                                    const float* __restrict__ rW2,
                                                    const float* __restrict__ rb2,
                                                    const float* __restrict__ eb2,
                                                    float* __restrict__ out,
                                                    int* __restrict__ cnt,
                                                    int* __restrict__ tokL,
                                                    float* __restrict__ wtL) {
  if (threadIdx.x < 4 * NCLS)
    out[blockIdx.x * 4 * NCLS + threadIdx.x] = eb2[threadIdx.x % NCLS];
  const int lane = threadIdx.x & 63;
  const int tok = blockIdx.x * 4 + (threadIdx.x >> 6);
  float r0 = 0.f, r1 = 0.f;
#pragma unroll
  for (int s = 0; s < 16; s++) {
    const float* p = partial + ((size_t)s * B_TOK + tok) * RHID;
    r0 += p[lane]; r1 += p[lane + 64];
  }
  r0 = fmaxf(r0 + rb1[lane], 0.f);
  r1 = fmaxf(r1 + rb1[lane + 64], 0.f);
  float lg[8];
#pragma unroll
  for (int c = 0; c < 8; c++)
    lg[c] = r0 * rW2[lane * 8 + c] + r1 * rW2[(lane + 64) * 8 + c];
#pragma unroll
  for (int off = 32; off >= 1; off >>= 1)
#pragma unroll
    for (int c = 0; c < 8; c++) lg[c] += __shfl_down(lg[c], off);
  if (lane == 0) {
    float m1 = -1e30f, m2 = -1e30f; int i1 = 0, i2 = 0;
#pragma unroll
    for (int c = 0; c < 8; c++) {
      float l = lg[c] + rb2[c];
      if (l > m1) { m2 = m1; i2 = i1; m1 = l; i1 = c; }
      else if (l > m2) { m2 = l; i2 = c; }
    }
    float w1 = 1.f / (1.f + expf(m2 - m1));
    float w2 = 1.f - w1;
    int p1 = atomicAdd(&cnt[i1], 1);
    tokL[i1 * B_TOK + p1] = tok; wtL[i1 * B_TOK + p1] = w1;
    int p2 = atomicAdd(&cnt[i2], 1);
    tokL[i2 * B_TOK + p2] = tok; wtL[i2 * B_TOK + p2] = w2;
  }
}

// ---- expert layer-1, split-K 2-way: ph[z][slot][hid] bf16 partials -------
// grid (16 nt, 23 tiles, 2 z). bf16 A from xbf (pre-converted), fp32 B packed
// to bf16 pairs in LDS. Pre-bias partial written via LDS transpose, 16B stores.
__global__ __launch_bounds__(256, 2) void k_expert(const unsigned short* __restrict__ xbf,
                                                   const float* __restrict__ eW1,
                                                   const int* __restrict__ cnt,
                                                   const int* __restrict__ tokL,
                                                   unsigned short* __restrict__ ph) {
  const int nt = blockIdx.x;
  const int z = blockIdx.z;
  int mt = blockIdx.y;
  int e, base_t = 0;
  for (e = 0; e < NEXP; e++) {
    int te = (cnt[e] + 127) >> 7;
    if (mt < te) break;
    mt -= te; base_t += te;
  }
  if (e >= NEXP) return;
  const int cnt_e = cnt[e];
  const int g = base_t + mt;       // global tile index

  __shared__ union {
    struct { unsigned short As[128][72]; unsigned Bs[32][132]; } a;  // 18432+16896
    unsigned short ehs[128][136];                                    // 34816
  } u;
  __shared__ int stok[128];

  const int tid = threadIdx.x;
  if (tid < 128) {
    int r = mt * 128 + tid;
    stok[tid] = (r < cnt_e) ? tokL[e * B_TOK + r] : 0;   // pad with token 0 (masked later)
  }
  __syncthreads();

  const int lane = tid & 63;
  const int wv = tid >> 6;
  const int wm = (wv & 1) * 64, wn = (wv >> 1) * 64;
  const int col = lane & 15, quad = lane >> 4;

  floatx4 acc[4][4];
#pragma unroll
  for (int mi = 0; mi < 4; mi++)
#pragma unroll
    for (int ni = 0; ni < 4; ni++) acc[mi][ni] = (floatx4)0.f;

  const float* W1e = eW1 + (size_t)e * DD_IN * EHID + (size_t)nt * 128;
  const size_t zb = (size_t)z * KHALF;

  // loader coords
  const int arow = tid >> 3, aseg = tid & 7;          // A: +32 rows per i
  const int bk2 = tid >> 5, bn4 = (tid & 31) << 2;    // B: +8 k2 per i

  uint4 pA[4];
  float4 pBa[4], pBb[4];

  // prologue: chunk 0
#pragma unroll
  for (int i = 0; i < 4; i++)
    pA[i] = *(const uint4*)(xbf + (size_t)stok[arow + i * 32] * DD_IN + zb + aseg * 8);
#pragma unroll
  for (int i = 0; i < 4; i++) {
    const float* src = W1e + (zb + (size_t)((bk2 + i * 8) * 2)) * EHID + bn4;
    pBa[i] = *(const float4*)src;
    pBb[i] = *(const float4*)(src + EHID);
  }

  for (int k0 = 0; k0 < KHALF; k0 += 64) {
#pragma unroll
    for (int i = 0; i < 4; i++)
      *(uint4*)&u.a.As[arow + i * 32][aseg * 8] = pA[i];
#pragma unroll
    for (int i = 0; i < 4; i++) {
      uint4 w;
      w.x = pk_bf16(pBa[i].x, pBb[i].x); w.y = pk_bf16(pBa[i].y, pBb[i].y);
      w.z = pk_bf16(pBa[i].z, pBb[i].z); w.w = pk_bf16(pBa[i].w, pBb[i].w);
      *(uint4*)&u.a.Bs[bk2 + i * 8][bn4] = w;
    }
    __syncthreads();
    if (k0 + 64 < KHALF) {
#pragma unroll
      for (int i = 0; i < 4; i++)
        pA[i] = *(const uint4*)(xbf + (size_t)stok[arow + i * 32] * DD_IN + zb + k0 + 64 + aseg * 8);
#pragma unroll
      for (int i = 0; i < 4; i++) {
        const float* src = W1e + (zb + (size_t)(k0 + 64 + (bk2 + i * 8) * 2)) * EHID + bn4;
        pBa[i] = *(const float4*)src;
        pBb[i] = *(const float4*)(src + EHID);
      }
    }
#pragma unroll
    for (int kk = 0; kk < 2; kk++) {
      short8 af[4], bf[4];
#pragma unroll
      for (int mi = 0; mi < 4; mi++)
        af[mi] = *(const short8*)&u.a.As[wm + mi * 16 + col][kk * 32 + quad * 8];
#pragma unroll
      for (int ni = 0; ni < 4; ni++) {
        int kb = kk * 16 + quad * 4;
        int nb = wn + ni * 16 + col;
        uint4 t;
        t.x = u.a.Bs[kb + 0][nb]; t.y = u.a.Bs[kb + 1][nb];
        t.z = u.a.Bs[kb + 2][nb]; t.w = u.a.Bs[kb + 3][nb];
        bf[ni] = __builtin_bit_cast(short8, t);
      }
#pragma unroll
      for (int mi = 0; mi < 4; mi++)
#pragma unroll
        for (int ni = 0; ni < 4; ni++)
          acc[mi][ni] = __builtin_amdgcn_mfma_f32_16x16x32_bf16(af[mi], bf[ni], acc[mi][ni], 0, 0, 0);
    }
    __syncthreads();
  }
  // epilogue: acc -> bf16 in LDS (transpose), then coalesced 16B stores to ph
#pragma unroll
  for (int ni = 0; ni < 4; ni++)
#pragma unroll
    for (int mi = 0; mi < 4; mi++)
#pragma unroll
      for (int r = 0; r < 4; r++)
        u.ehs[wm + mi * 16 + quad * 4 + r][wn + ni * 16 + col] = f2bf(acc[mi][ni][r]);
  __syncthreads();
  unsigned short* dst = ph + ((size_t)z * PH_ROWS + (size_t)g * 128) * EHID + (size_t)nt * 128;
  // 128 rows x 128 cols = 2048 uint4 stores = 8 iters x 256 threads
#pragma unroll
  for (int i = 0; i < 8; i++) {
    int s2 = tid + i * 256;
    int row = s2 >> 4, seg = s2 & 15;
    *(uint4*)(dst + (size_t)row * EHID + seg * 8) = *(const uint4*)&u.ehs[row][seg * 8];
  }
}

// ---- finalize: ph0+ph1 + bias, relu, layer-2 (10 cls), weighted combine ---
// grid (23 tiles, 8 hid-chunks of 256)
__global__ __launch_bounds__(256) void k_finalize(const unsigned short* __restrict__ ph,
                                                  const float* __restrict__ eb1,
                                                  const float* __restrict__ eW2,
                                                  const int* __restrict__ cnt,
                                                  const int* __restrict__ tokL,
                                                  const float* __restrict__ wtL,
                                                  float* __restrict__ out) {
  const int t = blockIdx.x, hc = blockIdx.y;
  int mt = t, e;
  for (e = 0; e < NEXP; e++) {
    int te = (cnt[e] + 127) >> 7;
    if (mt < te) break;
    mt -= te;
  }
  if (e >= NEXP) return;
  const int cnt_e = cnt[e];
  const int h0 = hc * 256;
  __shared__ float w2s[256 * NCLS];
  __shared__ float eb1s[256];
  const int tid = threadIdx.x;
#pragma unroll
  for (int i = 0; i < 10; i++) {
    int idx = tid + i * 256;
    w2s[idx] = eW2[((size_t)e * EHID + h0 + idx / NCLS) * NCLS + (idx % NCLS)];
  }
  eb1s[tid] = eb1[(size_t)e * EHID + h0 + tid];
  __syncthreads();

  const int slot = tid >> 1, half = tid & 1;
  const int r = mt * 128 + slot;
  const bool valid = r < cnt_e;
  float a10[NCLS];
#pragma unroll
  for (int c = 0; c < NCLS; c++) a10[c] = 0.f;

  const unsigned short* p0 = ph + ((size_t)t * 128 + slot) * EHID + h0 + half * 128;
  const unsigned short* p1 = p0 + (size_t)PH_ROWS * EHID;
  if (valid) {
    for (int hh = 0; hh < 128; hh += 8) {
      uint4 v0 = *(const uint4*)(p0 + hh);
      uint4 v1 = *(const uint4*)(p1 + hh);
      float eh[8];
      eh[0] = bflo(v0.x) + bflo(v1.x); eh[1] = bfhi(v0.x) + bfhi(v1.x);
      eh[2] = bflo(v0.y) + bflo(v1.y); eh[3] = bfhi(v0.y) + bfhi(v1.y);
      eh[4] = bflo(v0.z) + bflo(v1.z); eh[5] = bfhi(v0.z) + bfhi(v1.z);
      eh[6] = bflo(v0.w) + bflo(v1.w); eh[7] = bfhi(v0.w) + bfhi(v1.w);
#pragma unroll
      for (int j = 0; j < 8; j++) {
        int h = half * 128 + hh + j;
        float ev = fmaxf(eh[j] + eb1s[h], 0.f);
#pragma unroll
        for (int c = 0; c < NCLS; c++) a10[c] += ev * w2s[h * NCLS + c];
      }
    }
  }
  // combine the two halves (lane pairs)
#pragma unroll
  for (int c = 0; c < NCLS; c++) a10[c] += __shfl_down(a10[c], 1);
  if (valid && half == 0) {
    int tk = tokL[e * B_TOK + r];
    float wt = wtL[e * B_TOK + r];
#pragma unroll
    for (int c = 0; c < NCLS; c++)
      atomicAdd(out + (size_t)tk * NCLS + c, wt * a10[c]);
  }
}

// ---- launch -------------------------------------------------------------
extern "C" void kernel_launch(void* const* d_in, const int* in_sizes, int n_in,
                              void* d_out, int out_size, void* d_ws, size_t ws_size,
                              hipStream_t stream) {
  const float* x   = (const float*)d_in[0];
  const float* rW1 = (const float*)d_in[1];
  const float* rb1 = (const float*)d_in[2];
  const float* rW2 = (const float*)d_in[3];
  const float* rb2 = (const float*)d_in[4];
  const float* eW1 = (const float*)d_in[5];
  const float* eb1 = (const float*)d_in[6];
  const float* eW2 = (const float*)d_in[7];
  const float* eb2 = (const float*)d_in[8];
  float* out = (float*)d_out;

  char* ws = (char*)d_ws;
  int*            cnt     = (int*)(ws + 0);          // 8 ints
  int*            tokL    = (int*)(ws + 1024);       // 8*1024 int
  float*          wtL     = (float*)(ws + 33792);    // 8*1024 float
  unsigned short* xbf     = (unsigned short*)(ws + 66560);    // 1024*3072 bf16 = 6.29 MB
  float*          partial = (float*)(ws + 6358016);  // 16*1024*128 f32 = 8 MB
  unsigned short* ph      = (unsigned short*)(ws + 14746624); // 2*2944*2048 bf16 = 24.1 MB

  k_router_gemm<<<dim3(16, 16), 256, 0, stream>>>(x, rW1, partial, xbf, cnt);
  k_router_fin<<<256, 256, 0, stream>>>(partial, rb1, rW2, rb2, eb2, out, cnt, tokL, wtL);
  k_expert<<<dim3(16, NTILE_MAX, 2), 256, 0, stream>>>(xbf, eW1, cnt, tokL, ph);
  k_finalize<<<dim3(NTILE_MAX, 8), 256, 0, stream>>>(ph, eb1, eW2, cnt, tokL, wtL, out);
}

// Round 5
// 447.428 us; speedup vs baseline: 1.0202x; 1.0202x over previous
//
#include <hip/hip_runtime.h>
#include <cstdint>
#include <cstddef>

#define B_TOK 1024
#define DD_IN 3072
#define RHID 128
#define NEXP 8
#define EHID 2048
#define NCLS 10
#define KHALF 1536
#define NTILE_MAX 40              // sum ceil(cnt_e/64) <= 32+7+1
#define PH_ROWS (NTILE_MAX * 64)  // 2560

typedef __attribute__((ext_vector_type(8))) short short8;
typedef __attribute__((ext_vector_type(4))) float floatx4;

// ---- helpers ------------------------------------------------------------
__device__ __forceinline__ unsigned short f2bf(float f) {
  unsigned u = __builtin_bit_cast(unsigned, f);
  u += 0x7fffu + ((u >> 16) & 1u);           // RNE
  return (unsigned short)(u >> 16);
}
__device__ __forceinline__ unsigned pk_bf16(float a, float b) {
  return (unsigned)f2bf(a) | ((unsigned)f2bf(b) << 16);
}
__device__ __forceinline__ float bf2f(unsigned short h) {
  unsigned u = ((unsigned)h) << 16;
  return __builtin_bit_cast(float, u);
}
__device__ __forceinline__ float bflo(unsigned w) { return bf2f((unsigned short)(w & 0xffffu)); }
__device__ __forceinline__ float bfhi(unsigned w) { return bf2f((unsigned short)(w >> 16)); }

// ---- router GEMM1 (fp32, split-K S=16): partial[s][tok][hid] ------------
// Also converts x -> bf16 (xbf) and zeroes cnt[].
__global__ __launch_bounds__(256) void k_router_gemm(const float* __restrict__ x,
                                                     const float* __restrict__ rW1,
                                                     float* __restrict__ partial,
                                                     unsigned short* __restrict__ xbf,
                                                     int* __restrict__ cnt) {
  if (blockIdx.x == 0 && blockIdx.y == 0 && threadIdx.x < NEXP) cnt[threadIdx.x] = 0;
  const int ttile = blockIdx.x;   // 16 tiles x 64 tokens
  const int s = blockIdx.y;       // 16 K-slices x 192
  const int T0 = ttile * 64;
  const int K0 = s * 192;
  __shared__ float xs[16][64];     // [k][tok]
  __shared__ float wsm[16][132];   // [k][hid], +4 pad
  float acc[4][8];
#pragma unroll
  for (int i = 0; i < 4; i++)
#pragma unroll
    for (int j = 0; j < 8; j++) acc[i][j] = 0.f;
  const int tx = threadIdx.x & 15, ty = threadIdx.x >> 4;
  const int tid = threadIdx.x;

  const int xtok = tid >> 2, xk = (tid & 3) << 2;
  const int wk0 = tid >> 5, wf0 = (tid & 31) << 2;

  float4 pX, pW0, pW1;
  pX  = *(const float4*)(x + (size_t)(T0 + xtok) * DD_IN + K0 + xk);
  pW0 = *(const float4*)(rW1 + (size_t)(K0 + wk0) * RHID + wf0);
  pW1 = *(const float4*)(rW1 + (size_t)(K0 + wk0 + 8) * RHID + wf0);

  for (int kc = K0; kc < K0 + 192; kc += 16) {
    xs[xk + 0][xtok] = pX.x; xs[xk + 1][xtok] = pX.y;
    xs[xk + 2][xtok] = pX.z; xs[xk + 3][xtok] = pX.w;
    {
      uint2 u2;
      u2.x = pk_bf16(pX.x, pX.y); u2.y = pk_bf16(pX.z, pX.w);
      *(uint2*)(xbf + (size_t)(T0 + xtok) * DD_IN + kc + xk) = u2;
    }
    *(float4*)&wsm[wk0][wf0] = pW0;
    *(float4*)&wsm[wk0 + 8][wf0] = pW1;
    __syncthreads();
    if (kc + 16 < K0 + 192) {
      pX  = *(const float4*)(x + (size_t)(T0 + xtok) * DD_IN + kc + 16 + xk);
      pW0 = *(const float4*)(rW1 + (size_t)(kc + 16 + wk0) * RHID + wf0);
      pW1 = *(const float4*)(rW1 + (size_t)(kc + 16 + wk0 + 8) * RHID + wf0);
    }
#pragma unroll
    for (int kk = 0; kk < 16; kk++) {
      float wv[8], xv[4];
      *(float4*)&wv[0] = *(const float4*)&wsm[kk][tx * 8];
      *(float4*)&wv[4] = *(const float4*)&wsm[kk][tx * 8 + 4];
#pragma unroll
      for (int i = 0; i < 4; i++) xv[i] = xs[kk][ty * 4 + i];
#pragma unroll
      for (int i = 0; i < 4; i++)
#pragma unroll
        for (int j = 0; j < 8; j++) acc[i][j] += xv[i] * wv[j];
    }
    __syncthreads();
  }
#pragma unroll
  for (int i = 0; i < 4; i++) {
    float* p = partial + ((size_t)s * B_TOK + T0 + ty * 4 + i) * RHID + tx * 8;
    *(float4*)p = *(float4*)&acc[i][0];
    *(float4*)(p + 4) = *(float4*)&acc[i][4];
  }
}

// ---- router finalize ----------------------------------------------------
__global__ __launch_bounds__(256) void k_router_fin(const float* __restrict__ partial,
                                                    const float* __restrict__ rb1,
                                                    const float* __restrict__ rW2,
                                                    const float* __restrict__ rb2,
                                                    const float* __restrict__ eb2,
                                                    float* __restrict__ out,
                                                    int* __restrict__ cnt,
                                                    int* __restrict__ tokL,
                                                    float* __restrict__ wtL) {
  if (threadIdx.x < 4 * NCLS)
    out[blockIdx.x * 4 * NCLS + threadIdx.x] = eb2[threadIdx.x % NCLS];
  const int lane = threadIdx.x & 63;
  const int tok = blockIdx.x * 4 + (threadIdx.x >> 6);
  float r0 = 0.f, r1 = 0.f;
#pragma unroll
  for (int s = 0; s < 16; s++) {
    const float* p = partial + ((size_t)s * B_TOK + tok) * RHID;
    r0 += p[lane]; r1 += p[lane + 64];
  }
  r0 = fmaxf(r0 + rb1[lane], 0.f);
  r1 = fmaxf(r1 + rb1[lane + 64], 0.f);
  float lg[8];
#pragma unroll
  for (int c = 0; c < 8; c++)
    lg[c] = r0 * rW2[lane * 8 + c] + r1 * rW2[(lane + 64) * 8 + c];
#pragma unroll
  for (int off = 32; off >= 1; off >>= 1)
#pragma unroll
    for (int c = 0; c < 8; c++) lg[c] += __shfl_down(lg[c], off);
  if (lane == 0) {
    float m1 = -1e30f, m2 = -1e30f; int i1 = 0, i2 = 0;
#pragma unroll
    for (int c = 0; c < 8; c++) {
      float l = lg[c] + rb2[c];
      if (l > m1) { m2 = m1; i2 = i1; m1 = l; i1 = c; }
      else if (l > m2) { m2 = l; i2 = c; }
    }
    float w1 = 1.f / (1.f + expf(m2 - m1));
    float w2 = 1.f - w1;
    int p1 = atomicAdd(&cnt[i1], 1);
    tokL[i1 * B_TOK + p1] = tok; wtL[i1 * B_TOK + p1] = w1;
    int p2 = atomicAdd(&cnt[i2], 1);
    tokL[i2 * B_TOK + p2] = tok; wtL[i2 * B_TOK + p2] = w2;
  }
}

// ---- expert layer-1, M-tile=64, split-K 2-way ----------------------------
// grid (16 nt, 40 tiles, 2 z). ~1150 active blocks => ~4.5/CU resident.
__global__ __launch_bounds__(256) void k_expert(const unsigned short* __restrict__ xbf,
                                                const float* __restrict__ eW1,
                                                const int* __restrict__ cnt,
                                                const int* __restrict__ tokL,
                                                unsigned short* __restrict__ ph) {
  const int nt = blockIdx.x;
  const int z = blockIdx.z;
  int mt = blockIdx.y;
  int e, base_t = 0;
  for (e = 0; e < NEXP; e++) {
    int te = (cnt[e] + 63) >> 6;
    if (mt < te) break;
    mt -= te; base_t += te;
  }
  if (e >= NEXP) return;
  const int cnt_e = cnt[e];
  const int g = base_t + mt;       // global 64-row tile index

  __shared__ union {
    struct { unsigned short As[64][80]; unsigned Bs[32][132]; } a;  // 10240+16896
    unsigned short ehs[64][136];                                    // 17408
  } u;
  __shared__ int stok[64];

  const int tid = threadIdx.x;
  if (tid < 64) {
    int r = mt * 64 + tid;
    stok[tid] = (r < cnt_e) ? tokL[e * B_TOK + r] : 0;   // pad token 0 (masked later)
  }
  __syncthreads();

  const int lane = tid & 63;
  const int wv = tid >> 6;
  const int wn = wv * 32;                 // wave covers 32 N-cols, all 64 M
  const int col = lane & 15, quad = lane >> 4;

  floatx4 acc[4][2];
#pragma unroll
  for (int mi = 0; mi < 4; mi++)
#pragma unroll
    for (int ni = 0; ni < 2; ni++) acc[mi][ni] = (floatx4)0.f;

  const float* W1e = eW1 + (size_t)e * DD_IN * EHID + (size_t)nt * 128;
  const size_t zb = (size_t)z * KHALF;

  // loader coords: A 64x64 shorts = 512 uint4 -> 2/thread; B as before
  const int arow = tid >> 3, aseg = tid & 7;          // rows 0..31 (+32 for i=1)
  const int bk2 = tid >> 5, bn4 = (tid & 31) << 2;

  uint4 pA[2];
  float4 pBa[4], pBb[4];

  // prologue: K-chunk 0
#pragma unroll
  for (int i = 0; i < 2; i++)
    pA[i] = *(const uint4*)(xbf + (size_t)stok[arow + i * 32] * DD_IN + zb + aseg * 8);
#pragma unroll
  for (int i = 0; i < 4; i++) {
    const float* src = W1e + (zb + (size_t)((bk2 + i * 8) * 2)) * EHID + bn4;
    pBa[i] = *(const float4*)src;
    pBb[i] = *(const float4*)(src + EHID);
  }

  for (int k0 = 0; k0 < KHALF; k0 += 64) {
#pragma unroll
    for (int i = 0; i < 2; i++)
      *(uint4*)&u.a.As[arow + i * 32][aseg * 8] = pA[i];
#pragma unroll
    for (int i = 0; i < 4; i++) {
      uint4 w;
      w.x = pk_bf16(pBa[i].x, pBb[i].x); w.y = pk_bf16(pBa[i].y, pBb[i].y);
      w.z = pk_bf16(pBa[i].z, pBb[i].z); w.w = pk_bf16(pBa[i].w, pBb[i].w);
      *(uint4*)&u.a.Bs[bk2 + i * 8][bn4] = w;
    }
    __syncthreads();
    if (k0 + 64 < KHALF) {
#pragma unroll
      for (int i = 0; i < 2; i++)
        pA[i] = *(const uint4*)(xbf + (size_t)stok[arow + i * 32] * DD_IN + zb + k0 + 64 + aseg * 8);
#pragma unroll
      for (int i = 0; i < 4; i++) {
        const float* src = W1e + (zb + (size_t)(k0 + 64 + (bk2 + i * 8) * 2)) * EHID + bn4;
        pBa[i] = *(const float4*)src;
        pBb[i] = *(const float4*)(src + EHID);
      }
    }
#pragma unroll
    for (int kk = 0; kk < 2; kk++) {
      short8 af[4], bf[2];
#pragma unroll
      for (int mi = 0; mi < 4; mi++)
        af[mi] = *(const short8*)&u.a.As[mi * 16 + col][kk * 32 + quad * 8];
#pragma unroll
      for (int ni = 0; ni < 2; ni++) {
        int kb = kk * 16 + quad * 4;
        int nb = wn + ni * 16 + col;
        uint4 t;
        t.x = u.a.Bs[kb + 0][nb]; t.y = u.a.Bs[kb + 1][nb];
        t.z = u.a.Bs[kb + 2][nb]; t.w = u.a.Bs[kb + 3][nb];
        bf[ni] = __builtin_bit_cast(short8, t);
      }
#pragma unroll
      for (int mi = 0; mi < 4; mi++)
#pragma unroll
        for (int ni = 0; ni < 2; ni++)
          acc[mi][ni] = __builtin_amdgcn_mfma_f32_16x16x32_bf16(af[mi], bf[ni], acc[mi][ni], 0, 0, 0);
    }
    __syncthreads();
  }
  // epilogue: acc -> bf16 LDS transpose, then coalesced 16B stores to ph
#pragma unroll
  for (int ni = 0; ni < 2; ni++)
#pragma unroll
    for (int mi = 0; mi < 4; mi++)
#pragma unroll
      for (int r = 0; r < 4; r++)
        u.ehs[mi * 16 + quad * 4 + r][wn + ni * 16 + col] = f2bf(acc[mi][ni][r]);
  __syncthreads();
  unsigned short* dst = ph + ((size_t)z * PH_ROWS + (size_t)g * 64) * EHID + (size_t)nt * 128;
  // 64 rows x 128 cols = 1024 uint4 = 4 iters x 256 threads
#pragma unroll
  for (int i = 0; i < 4; i++) {
    int s2 = tid + i * 256;
    int row = s2 >> 4, seg = s2 & 15;
    *(uint4*)(dst + (size_t)row * EHID + seg * 8) = *(const uint4*)&u.ehs[row][seg * 8];
  }
}

// ---- finalize: ph0+ph1 + bias, relu, layer-2, weighted combine -----------
// grid (40 tiles, 8 hid-chunks of 256); 4 threads per token-slot
__global__ __launch_bounds__(256) void k_finalize(const unsigned short* __restrict__ ph,
                                                  const float* __restrict__ eb1,
                                                  const float* __restrict__ eW2,
                                                  const int* __restrict__ cnt,
                                                  const int* __restrict__ tokL,
                                                  const float* __restrict__ wtL,
                                                  float* __restrict__ out) {
  const int t = blockIdx.x, hc = blockIdx.y;
  int mt = t, e;
  for (e = 0; e < NEXP; e++) {
    int te = (cnt[e] + 63) >> 6;
    if (mt < te) break;
    mt -= te;
  }
  if (e >= NEXP) return;
  const int cnt_e = cnt[e];
  const int h0 = hc * 256;
  __shared__ float w2s[256 * NCLS];
  __shared__ float eb1s[256];
  const int tid = threadIdx.x;
#pragma unroll
  for (int i = 0; i < 10; i++) {
    int idx = tid + i * 256;
    w2s[idx] = eW2[((size_t)e * EHID + h0 + idx / NCLS) * NCLS + (idx % NCLS)];
  }
  eb1s[tid] = eb1[(size_t)e * EHID + h0 + tid];
  __syncthreads();

  const int slot = tid >> 2, q = tid & 3;   // 4 threads per slot, 64 hid each
  const int r = mt * 64 + slot;
  const bool valid = r < cnt_e;
  float a10[NCLS];
#pragma unroll
  for (int c = 0; c < NCLS; c++) a10[c] = 0.f;

  const unsigned short* p0 = ph + ((size_t)t * 64 + slot) * EHID + h0 + q * 64;
  const unsigned short* p1 = p0 + (size_t)PH_ROWS * EHID;
  if (valid) {
    for (int hh = 0; hh < 64; hh += 8) {
      uint4 v0 = *(const uint4*)(p0 + hh);
      uint4 v1 = *(const uint4*)(p1 + hh);
      float eh[8];
      eh[0] = bflo(v0.x) + bflo(v1.x); eh[1] = bfhi(v0.x) + bfhi(v1.x);
      eh[2] = bflo(v0.y) + bflo(v1.y); eh[3] = bfhi(v0.y) + bfhi(v1.y);
      eh[4] = bflo(v0.z) + bflo(v1.z); eh[5] = bfhi(v0.z) + bfhi(v1.z);
      eh[6] = bflo(v0.w) + bflo(v1.w); eh[7] = bfhi(v0.w) + bfhi(v1.w);
#pragma unroll
      for (int j = 0; j < 8; j++) {
        int h = q * 64 + hh + j;
        float ev = fmaxf(eh[j] + eb1s[h], 0.f);
#pragma unroll
        for (int c = 0; c < NCLS; c++) a10[c] += ev * w2s[h * NCLS + c];
      }
    }
  }
  // reduce the 4 per-slot threads (lanes q=0..3 within a wave)
#pragma unroll
  for (int c = 0; c < NCLS; c++) a10[c] += __shfl_down(a10[c], 2);
#pragma unroll
  for (int c = 0; c < NCLS; c++) a10[c] += __shfl_down(a10[c], 1);
  if (valid && q == 0) {
    int tk = tokL[e * B_TOK + r];
    float wt = wtL[e * B_TOK + r];
#pragma unroll
    for (int c = 0; c < NCLS; c++)
      atomicAdd(out + (size_t)tk * NCLS + c, wt * a10[c]);
  }
}

// ---- launch -------------------------------------------------------------
extern "C" void kernel_launch(void* const* d_in, const int* in_sizes, int n_in,
                              void* d_out, int out_size, void* d_ws, size_t ws_size,
                              hipStream_t stream) {
  const float* x   = (const float*)d_in[0];
  const float* rW1 = (const float*)d_in[1];
  const float* rb1 = (const float*)d_in[2];
  const float* rW2 = (const float*)d_in[3];
  const float* rb2 = (const float*)d_in[4];
  const float* eW1 = (const float*)d_in[5];
  const float* eb1 = (const float*)d_in[6];
  const float* eW2 = (const float*)d_in[7];
  const float* eb2 = (const float*)d_in[8];
  float* out = (float*)d_out;

  char* ws = (char*)d_ws;
  int*            cnt     = (int*)(ws + 0);          // 8 ints
  int*            tokL    = (int*)(ws + 1024);       // 8*1024 int
  float*          wtL     = (float*)(ws + 33792);    // 8*1024 float
  unsigned short* xbf     = (unsigned short*)(ws + 66560);    // 1024*3072 bf16
  float*          partial = (float*)(ws + 6358016);  // 16*1024*128 f32 = 8 MB
  unsigned short* ph      = (unsigned short*)(ws + 14746624); // 2*2560*2048 bf16 = 21 MB

  k_router_gemm<<<dim3(16, 16), 256, 0, stream>>>(x, rW1, partial, xbf, cnt);
  k_router_fin<<<256, 256, 0, stream>>>(partial, rb1, rW2, rb2, eb2, out, cnt, tokL, wtL);
  k_expert<<<dim3(16, NTILE_MAX, 2), 256, 0, stream>>>(xbf, eW1, cnt, tokL, ph);
  k_finalize<<<dim3(NTILE_MAX, 8), 256, 0, stream>>>(ph, eb1, eW2, cnt, tokL, wtL, out);
}